// Round 3
// 535.325 us; speedup vs baseline: 1.0843x; 1.0843x over previous
//
#include <hip/hip_runtime.h>
#include <stdint.h>

typedef __bf16 bf16;
typedef __bf16 bf16x8 __attribute__((ext_vector_type(8)));
typedef float  f32x4  __attribute__((ext_vector_type(4)));
typedef float  fvec4  __attribute__((ext_vector_type(4)));

#define B_DIM 16384
#define H_DIM 1024
#define K_DIM 2048
#define NKT   32      // K_DIM / 64 K-tiles

// ---- async global->LDS, 16B per lane ----
__device__ __forceinline__ void g2l16(const void* g, void* l) {
    __builtin_amdgcn_global_load_lds(
        (const __attribute__((address_space(1))) void*)g,
        (__attribute__((address_space(3))) void*)l,
        16, 0, 0);
}

__device__ __forceinline__ float sigm_fast(float x) {
    x = fminf(fmaxf(x, -40.f), 40.f);
    float e = __builtin_amdgcn_exp2f(-1.4426950408889634f * x);
    return __builtin_amdgcn_rcpf(1.0f + e);
}
__device__ __forceinline__ float tanh_fast(float x) {
    x = fminf(fmaxf(x, -40.f), 40.f);
    float e = __builtin_amdgcn_exp2f(-2.8853900817779268f * x);   // exp(-2x)
    return (1.0f - e) * __builtin_amdgcn_rcpf(1.0f + e);
}

__device__ __forceinline__ bf16x8 cvt8(const float* __restrict__ src) {
    fvec4 a = __builtin_nontemporal_load((const fvec4*)src);
    fvec4 b = __builtin_nontemporal_load((const fvec4*)(src + 4));
    bf16x8 o = { (bf16)a.x, (bf16)a.y, (bf16)a.z, (bf16)a.w,
                 (bf16)b.x, (bf16)b.y, (bf16)b.z, (bf16)b.w };
    return o;
}

// ---- ONE streaming convert kernel (UNCHANGED) ----
__global__ __launch_bounds__(256) void cvt_all(const float* __restrict__ x,
                                               const float* __restrict__ h,
                                               const float* __restrict__ Wx,
                                               const float* __restrict__ Rh,
                                               const float* __restrict__ bx,
                                               const float* __restrict__ bh,
                                               bf16* __restrict__ U,
                                               bf16* __restrict__ W,
                                               float* __restrict__ bb) {
    int b = blockIdx.x;
    if (b < 16384) {
        const float* src0 = (b < 8192) ? x : h;
        int half = (b < 8192) ? 0 : 1024;
        int gid  = (b & 8191) * 256 + threadIdx.x;
        int row  = gid >> 7;
        int c    = gid & 127;
        bf16x8 o = cvt8(src0 + ((size_t)row << 10) + (c << 3));
        *(bf16x8*)(U + ((size_t)row << 11) + half + (c << 3)) = o;
    } else {
        int gid = (b - 16384) * 256 + threadIdx.x;
        if (gid < 524288) {
            int row = gid >> 7;
            int c   = gid & 127;
            bf16x8 o = cvt8(Wx + ((size_t)row << 10) + (c << 3));
            *(bf16x8*)(W + ((size_t)row << 11) + (c << 3)) = o;
        } else {
            int g2  = gid - 524288;
            int row = g2 >> 7;
            int c   = g2 & 127;
            bf16x8 o = cvt8(Rh + ((size_t)row << 10) + (c << 3));
            *(bf16x8*)(W + ((size_t)row << 11) + 1024 + (c << 3)) = o;
        }
        if (gid < 4096) bb[gid] = bx[gid] + bh[gid];
    }
}

// ---- fused GEMM (pre = U.W^T + bb) + LSTM epilogue, 8-phase 256^2 schedule ----
// BM=BN=256, BK=64, 8 waves (2M x 4N), per-wave 128x64 out (acc[8][4] f32x4).
// B tile row r -> gate (r>>4)&3, h_local (r>>6)*16+(r&15): wave wn holds all 4
// gates for h = h0 + wn*16 + lc  => lane-local LSTM epilogue (ni == gate).
// LDS: As/Bs[2 dbuf][256x64] = 128 KiB. XOR chunk-swizzle c^(row&7) via
// pre-swizzled GLOBAL source (global_load_lds dest must be linear).
//
// Schedule per K-tile kt (read buf=kt&1; 2 barriers/phase; vmcnt counted):
//   P1: ds_read A mi0-3 (8xb128) + B n0-1 (4) | stage kt+1.A-hi  | 16 MFMA
//   P2: ds_read B n2-3 (4)                    | stage kt+1.B-hi  | 16 MFMA
//   P3: ds_read A mi4-7 (8)                   | stage kt+2.B-lo  | 16 MFMA
//   P4: (no ds_read)                          | stage kt+2.A-lo  | 16 MFMA
//       vmcnt(4) (2 half-tiles stay in flight; NEVER 0 mid-loop) + barrier
// Safety: region staged at phase p was last ds_read at phase <= p-1 (reads
// drained by that wave's own lgkmcnt(0) before the phase-closing barrier);
// vmcnt(4)+barrier at P4 guarantees kt+1 fully landed before kt+1.P1 reads.
// Tail: kt==30 drains vmcnt(0); kt==31 computes only.
// NOTE: kt loop is unroll(disable)d — the fully-unrolled body (~15k instrs
// dense with inline asm + convergent barriers) is a compile-time hazard.
__global__ __launch_bounds__(512, 2)
void lstm_fused(const bf16* __restrict__ U, const bf16* __restrict__ W,
                const float* __restrict__ bb, const float* __restrict__ cprev,
                float* __restrict__ out) {
    __shared__ __align__(16) bf16 As[2][256 * 64];
    __shared__ __align__(16) bf16 Bs[2][256 * 64];

    const int tid  = threadIdx.x;
    const int wave = tid >> 6;
    const int lane = tid & 63;
    const int quad = lane >> 4;
    const int lc   = lane & 15;
    const int wm   = wave >> 2;          // 0..1  (M half)
    const int wn   = wave & 3;           // 0..3  (N quarter)

    // XCD-aware mapping: 1024 blocks, 8 XCDs x 128. Each XCD owns 2 h-slices
    // and sweeps all 64 m-tiles -> B panel stays hot in XCD-L2, U shared via L3.
    int bid   = blockIdx.x;
    int xcd   = bid & 7;
    int t     = bid >> 3;                // 0..127
    int h_idx = (xcd << 1) + (t >> 6);   // 0..15
    int m_idx = t & 63;                  // 0..63
    const int m0 = m_idx << 8;           // 256 U-rows per tile
    const int h0 = h_idx << 6;           // 64 h per tile

    // ---- per-thread staging addresses (32-bit offsets: U=64MiB, W=16MiB) ----
    // half-tile = 128 rows x 64 cols bf16 = 16KB = 512 thr x 2 x 16B.
    // slot = ld*512+tid; LDS dest linear slot*16 (wave-uniform base + lane*16);
    // global col chunk pre-swizzled: chunk ^ (row&7).
    uint32_t offA[2][2], offB[2][2];     // [ld][half]
    uint32_t lofs[2];
#pragma unroll
    for (int ld = 0; ld < 2; ++ld) {
        int slot  = (ld << 9) + tid;
        int row   = slot >> 3;           // 0..127 within half
        int chunk = slot & 7;
        int colb  = (chunk ^ (row & 7)) << 4;
        lofs[ld]  = slot << 4;
#pragma unroll
        for (int hf = 0; hf < 2; ++hf) {
            int arow = m0 + (hf << 7) + row;
            offA[ld][hf] = ((uint32_t)arow << 12) + colb;
            int br   = (hf << 7) + row;                    // B tile row 0..255
            int gate = (br >> 4) & 3;
            int hl   = ((br >> 6) << 4) + (br & 15);
            int wrow = (gate << 10) + h0 + hl;
            offB[ld][hf] = ((uint32_t)wrow << 12) + colb;
        }
    }
    const char* Ub = (const char*)U;     // row stride 4096 B
    const char* Wb = (const char*)W;     // row stride 4096 B
    char* AsB = (char*)As;
    char* BsB = (char*)Bs;

#define STG_A(hf, dbuf, ktt) do {                                              \
        g2l16(Ub + offA[0][hf] + ((ktt) << 7),                                 \
              AsB + ((dbuf) << 15) + ((hf) << 14) + lofs[0]);                  \
        g2l16(Ub + offA[1][hf] + ((ktt) << 7),                                 \
              AsB + ((dbuf) << 15) + ((hf) << 14) + lofs[1]);                  \
    } while (0)
#define STG_B(hf, dbuf, ktt) do {                                              \
        g2l16(Wb + offB[0][hf] + ((ktt) << 7),                                 \
              BsB + ((dbuf) << 15) + ((hf) << 14) + lofs[0]);                  \
        g2l16(Wb + offB[1][hf] + ((ktt) << 7),                                 \
              BsB + ((dbuf) << 15) + ((hf) << 14) + lofs[1]);                  \
    } while (0)

// fragment read: global chunk (ks*4+quad), swizzled by row&7 == lc&7
#define LDFRAG(BASEB, dbuf, row, ks)                                           \
    (*(const bf16x8*)((BASEB) + ((dbuf) << 15) + ((row) << 7) +                \
                      ((((((ks) << 2)) + quad) ^ (lc & 7)) << 4)))

#define MFMA_Q(MIBASE, NIBASE)                                                 \
    do {                                                                       \
        _Pragma("unroll")                                                      \
        for (int mi = 0; mi < 4; ++mi)                                         \
            _Pragma("unroll")                                                  \
            for (int ni = 0; ni < 2; ++ni)                                     \
                _Pragma("unroll")                                              \
                for (int ks = 0; ks < 2; ++ks)                                 \
                    acc[(MIBASE) + mi][(NIBASE) + ni] =                        \
                        __builtin_amdgcn_mfma_f32_16x16x32_bf16(               \
                            a_[mi][ks], b_[(NIBASE) + ni][ks],                 \
                            acc[(MIBASE) + mi][(NIBASE) + ni], 0, 0, 0);       \
    } while (0)

    f32x4 acc[8][4];
#pragma unroll
    for (int mi = 0; mi < 8; ++mi)
#pragma unroll
        for (int ni = 0; ni < 4; ++ni)
            acc[mi][ni] = (f32x4){0.f, 0.f, 0.f, 0.f};

    // ---- prologue: issue kt0 {Blo,Alo,Ahi,Bhi} + kt1 {Blo,Alo} (12 loads),
    // then vmcnt(4): kt0 fully landed, kt1.{Blo,Alo} may stay in flight.
    STG_B(0, 0, 0);
    STG_A(0, 0, 0);
    STG_A(1, 0, 0);
    STG_B(1, 0, 0);
    STG_B(0, 1, 1);
    STG_A(0, 1, 1);
    asm volatile("s_waitcnt vmcnt(4)" ::: "memory");
    __builtin_amdgcn_s_barrier();

    const int rA0 = (wm << 7) + lc;      // A row base, mi-half 0
    const int rB0 = (wn << 6) + lc;      // B row base

    bf16x8 a_[4][2];                     // current A mi-half frags [mi&3][ks]
    bf16x8 b_[4][2];                     // all B frags for the K-tile [ni][ks]

#pragma clang loop unroll(disable)
    for (int kt = 0; kt < NKT; ++kt) {
        const int buf = kt & 1;

        // ---------------- P1 ----------------
#pragma unroll
        for (int mi = 0; mi < 4; ++mi) {
            a_[mi][0] = LDFRAG(AsB, buf, rA0 + (mi << 4), 0);
            a_[mi][1] = LDFRAG(AsB, buf, rA0 + (mi << 4), 1);
        }
#pragma unroll
        for (int ni = 0; ni < 2; ++ni) {
            b_[ni][0] = LDFRAG(BsB, buf, rB0 + (ni << 4), 0);
            b_[ni][1] = LDFRAG(BsB, buf, rB0 + (ni << 4), 1);
        }
        if (kt < NKT - 1) STG_A(1, buf ^ 1, kt + 1);
        __builtin_amdgcn_s_barrier();
        asm volatile("s_waitcnt lgkmcnt(0)" ::: "memory");
        __builtin_amdgcn_s_setprio(1);
        MFMA_Q(0, 0);
        __builtin_amdgcn_s_setprio(0);
        __builtin_amdgcn_s_barrier();

        // ---------------- P2 ----------------
#pragma unroll
        for (int ni = 2; ni < 4; ++ni) {
            b_[ni][0] = LDFRAG(BsB, buf, rB0 + (ni << 4), 0);
            b_[ni][1] = LDFRAG(BsB, buf, rB0 + (ni << 4), 1);
        }
        if (kt < NKT - 1) STG_B(1, buf ^ 1, kt + 1);
        __builtin_amdgcn_s_barrier();
        asm volatile("s_waitcnt lgkmcnt(0)" ::: "memory");
        __builtin_amdgcn_s_setprio(1);
        MFMA_Q(0, 2);
        __builtin_amdgcn_s_setprio(0);
        __builtin_amdgcn_s_barrier();

        // ---------------- P3 ----------------
#pragma unroll
        for (int mi = 0; mi < 4; ++mi) {
            a_[mi][0] = LDFRAG(AsB, buf, rA0 + 64 + (mi << 4), 0);
            a_[mi][1] = LDFRAG(AsB, buf, rA0 + 64 + (mi << 4), 1);
        }
        if (kt < NKT - 2) STG_B(0, buf, kt + 2);
        __builtin_amdgcn_s_barrier();
        asm volatile("s_waitcnt lgkmcnt(0)" ::: "memory");
        __builtin_amdgcn_s_setprio(1);
        MFMA_Q(4, 0);
        __builtin_amdgcn_s_setprio(0);
        __builtin_amdgcn_s_barrier();

        // ---------------- P4 ----------------
        if (kt < NKT - 2) STG_A(0, buf, kt + 2);
        __builtin_amdgcn_s_barrier();
        __builtin_amdgcn_s_setprio(1);
        MFMA_Q(4, 2);
        __builtin_amdgcn_s_setprio(0);
        if (kt < NKT - 2) {
            asm volatile("s_waitcnt vmcnt(4)" ::: "memory");
        } else if (kt == NKT - 2) {
            asm volatile("s_waitcnt vmcnt(0)" ::: "memory");
        }
        __builtin_amdgcn_s_barrier();
    }

    // ---- LSTM epilogue: C/D layout col=lane&15, row=quad*4+reg; ni == gate ----
    const int h = h0 + (wn << 4) + lc;
    float bias[4];
#pragma unroll
    for (int g = 0; g < 4; ++g) bias[g] = bb[(g << 10) + h];

    float* out_h = out;
    float* out_c = out + (size_t)B_DIM * H_DIM;
#pragma unroll
    for (int mi = 0; mi < 8; ++mi) {
#pragma unroll
        for (int r = 0; r < 4; ++r) {
            int brow  = m0 + (wm << 7) + (mi << 4) + (quad << 2) + r;
            size_t rb = (size_t)brow << 10;
            float zp = acc[mi][0][r] + bias[0];
            float ip = acc[mi][1][r] + bias[1];
            float fp = acc[mi][2][r] + bias[2];
            float op = acc[mi][3][r] + bias[3];
            float zz = tanh_fast(zp);
            float ii = sigm_fast(ip);
            float ff = sigm_fast(fp);
            float oo = sigm_fast(op);
            float cp = cprev[rb + h];
            float cn = ff * cp + ii * zz;
            float hn = oo * tanh_fast(cn);
            out_h[rb + h] = hn;
            out_c[rb + h] = cn;
        }
    }
}

extern "C" void kernel_launch(void* const* d_in, const int* in_sizes, int n_in,
                              void* d_out, int out_size, void* d_ws, size_t ws_size,
                              hipStream_t stream) {
    const float* x  = (const float*)d_in[0];
    const float* hp = (const float*)d_in[1];
    const float* cp = (const float*)d_in[2];
    const float* Wx = (const float*)d_in[3];
    const float* bx = (const float*)d_in[4];
    const float* Rh = (const float*)d_in[5];
    const float* bh = (const float*)d_in[6];

    // workspace: U 64 MiB | W 16 MiB | bb 16 KiB
    bf16*  U  = (bf16*)d_ws;
    bf16*  W  = (bf16*)((char*)d_ws + (size_t)67108864);
    float* bb = (float*)((char*)d_ws + (size_t)67108864 + 16777216);

    cvt_all<<<20480, 256, 0, stream>>>(x, hp, Wx, Rh, bx, bh, U, W, bb);
    lstm_fused<<<1024, 512, 0, stream>>>(U, W, bb, cp, (float*)d_out);
}